// Round 11
// baseline (149.558 us; speedup 1.0000x reference)
//
#include <hip/hip_runtime.h>

#define BATCH 8192
#define DIM   512
// 64 straddle + 960 full above-diag + 128 quarter tiles (last 32 parents split 4-way in j)
#define NTILE 1152
#define NFIN  128          // final-kernel blocks

typedef __attribute__((ext_vector_type(4))) float  f32x4;
typedef __attribute__((ext_vector_type(8))) __bf16 bf16x8;

__device__ __forceinline__ unsigned short f2bf(float x) {
  unsigned u = __float_as_uint(x);
  u = (u + 0x7FFFu + ((u >> 16) & 1u)) >> 16;   // RNE
  return (unsigned short)u;
}

__device__ __forceinline__ void load_lds16(const void* g, void* l) {
  __builtin_amdgcn_global_load_lds(
      (__attribute__((address_space(1))) void*)(g),
      (__attribute__((address_space(3))) void*)(l), 16, 0, 0);
}

// monotone float <-> uint encoding (order-preserving); sentinels 0x00000000 / 0xFFFFFFFF
__device__ __forceinline__ unsigned enc(float f) {
  unsigned u = __float_as_uint(f);
  return u ^ (unsigned)(((int)u >> 31) | 0x80000000);
}
__device__ __forceinline__ float dec(unsigned k) {
  unsigned u = (k & 0x80000000u) ? (k ^ 0x80000000u) : ~k;
  return __uint_as_float(u);
}

// ---------------- prep: fp32->bf16, row norms, sentinel seeding, ctrl zeroing --------------
__global__ __launch_bounds__(256) void prep_kernel(
    const float* __restrict__ X, unsigned short* __restrict__ Xb,
    float* __restrict__ sq, unsigned* __restrict__ ctrl,
    uint4* __restrict__ pos4, uint4* __restrict__ neg4) {
  int gid = blockIdx.x * 256 + threadIdx.x;
  if (gid == 0) {
    ((float*)ctrl)[0] = 0.f;                   // sum of terms
    ((float*)ctrl)[1] = 0.f;                   // count
    ctrl[2] = 0u;                              // finish ticket
    ctrl[3] = 0u;                              // tile queue head
  }
  if (gid < 196608) {                          // 96 slots * 8192 * 4B / 16B
    pos4[gid] = (uint4){0u, 0u, 0u, 0u};       // enc-min sentinel (loses every max)
    neg4[gid] = (uint4){~0u, ~0u, ~0u, ~0u};   // enc-max sentinel (loses every min)
  }
  int wave = threadIdx.x >> 6, lane = threadIdx.x & 63;
  int row = blockIdx.x * 4 + wave;             // 2048 blocks * 4 waves = 8192 rows
  const float4* xr = (const float4*)(X + (size_t)row * DIM);
  float4 a = xr[lane * 2];
  float4 b = xr[lane * 2 + 1];
  float s = a.x*a.x + a.y*a.y + a.z*a.z + a.w*a.w
          + b.x*b.x + b.y*b.y + b.z*b.z + b.w*b.w;
  uint4 p;
  p.x = (unsigned)f2bf(a.x) | ((unsigned)f2bf(a.y) << 16);
  p.y = (unsigned)f2bf(a.z) | ((unsigned)f2bf(a.w) << 16);
  p.z = (unsigned)f2bf(b.x) | ((unsigned)f2bf(b.y) << 16);
  p.w = (unsigned)f2bf(b.z) | ((unsigned)f2bf(b.w) << 16);
  ((uint4*)(Xb + (size_t)row * DIM))[lane] = p;
  #pragma unroll
  for (int off = 32; off > 0; off >>= 1) s += __shfl_down(s, off);
  if (lane == 0) sq[row] = s;
}

// ---------------- tile decode (R3-verbatim queue order) ---------------------------
__device__ __forceinline__ void decode_tile(int t, int& It, int& Js, int& q, bool& strad) {
  It = 0; Js = 0; q = -1; strad = false;
  if (t < 64) { It = t; Js = t >> 1; strad = true; return; }
  int u;
  if (t < 1024) u = t - 64;                       // full above-diag: u in [0,960)
  else { q = (t - 1024) & 3; u = 960 + ((t - 1024) >> 2); }  // quarters: u in [960,992)
  for (int s = 0; s < 64; s++) {
    int c = 31 - (s >> 1);
    if (u < c) { It = s; Js = (s >> 1) + 1 + u; return; }
    u -= c;
  }
}

// ---------------- staging of one BK=64 slab (R3 layout, XOR swizzle) --------------
template<int NI>
__device__ __forceinline__ void stage_slab(
    const unsigned short* __restrict__ Xb, int i0, int jw, int k0,
    unsigned short* Asm, unsigned short* Bsm, int wave, int rc, int gcol) {
  #pragma unroll
  for (int tt = 0; tt < 4; tt++) {
    int c = wave * 4 + tt;
    int row = c * 8 + rc;
    load_lds16(Xb + (size_t)(i0 + row) * DIM + k0 + gcol, &Asm[c * 512]);
  }
  #pragma unroll
  for (int tt = 0; tt < NI; tt++) {          // NI loads/thread covers NI*32 B-rows
    int c = wave * NI + tt;
    int row = c * 8 + rc;
    load_lds16(Xb + (size_t)(jw + row) * DIM + k0 + gcol, &Bsm[c * 512]);
  }
}

// ---------------- K-loop with step-0 PRE-STAGED by the caller ---------------------
// Iteration 0 skips staging (loads already in flight, issued under the previous
// tile's epilogue part B); leading __syncthreads drains vmcnt. NO trailing sync
// after the last compute — the caller's tshare-publish barrier provides it.
template<int NI>
__device__ __forceinline__ void gemm_pf(
    const unsigned short* __restrict__ Xb, int i0, int jw,
    unsigned short* Asm, unsigned short* Bsm,
    int wave, int wm, int wn, int quad, int lc, int rc, int gcol,
    f32x4 (&acc)[4][8]) {
  for (int k0 = 0; k0 < DIM; k0 += 64) {
    if (k0) stage_slab<NI>(Xb, i0, jw, k0, Asm, Bsm, wave, rc, gcol);
    __syncthreads();
    #pragma unroll
    for (int kk = 0; kk < 64; kk += 32) {
      int kc = kk >> 3;
      int asel = ((kc + quad) ^ (lc & 7)) * 8;
      bf16x8 af[4], bfr[NI];
      #pragma unroll
      for (int mi = 0; mi < 4; mi++)
        af[mi] = *(const bf16x8*)&Asm[(wm * 64 + mi * 16 + lc) * 64 + asel];
      #pragma unroll
      for (int ni = 0; ni < NI; ni++)
        bfr[ni] = *(const bf16x8*)&Bsm[(wn * (NI * 16) + ni * 16 + lc) * 64 + asel];
      #pragma unroll
      for (int mi = 0; mi < 4; mi++)
        #pragma unroll
        for (int ni = 0; ni < NI; ni++)
          acc[mi][ni] = __builtin_amdgcn_mfma_f32_16x16x32_bf16(
              af[mi], bfr[ni], acc[mi][ni], 0, 0, 0);
    }
    if (k0 < DIM - 64) __syncthreads();
  }
}

// ---------------- epilogue part A: consume acc -> rpos/rneg/jp/jn (registers only) -------
// After this returns, acc is DEAD: the caller may then issue the next tile's
// prefetch without acc inflating the live set (R10's spill: prefetch before
// epilogue kept 128 acc regs live across it -> 15MB scratch WRITE).
template<bool STRAD, int NI, int WNS>
__device__ __forceinline__ void epi_acc(
    const f32x4 (&acc)[4][8], const float* __restrict__ sq,
    const int* __restrict__ labels,
    int i0, int jwin, int wm, int wn, int quad, int lc,
    float (&rpos)[16], float (&rneg)[16], float (&jp)[8], float (&jn)[8]) {
  float sqj_r[NI]; int labj_r[NI];
  #pragma unroll
  for (int ni = 0; ni < NI; ni++) {
    int j = jwin + wn * WNS + ni * 16 + lc;
    sqj_r[ni] = sq[j]; labj_r[ni] = labels[j];
  }
  #pragma unroll
  for (int x = 0; x < NI; x++) { jp[x] = -3e38f; jn[x] = 3e38f; }
  #pragma unroll
  for (int mi = 0; mi < 4; mi++) {
    #pragma unroll
    for (int r = 0; r < 4; r++) {
      int ig = i0 + wm * 64 + mi * 16 + quad * 4 + r;
      int li = labels[ig];
      float si = sq[ig];
      float rp = -3e38f, rn = 3e38f;
      #pragma unroll
      for (int ni = 0; ni < NI; ni++) {
        float a = acc[mi][ni][r];
        float v = fmaf(-2.f, a, sqj_r[ni]);        // sq_j - 2dot (sq_i added at end)
        bool same = (li == labj_r[ni]);
        bool posok = same;
        if (STRAD) posok = same && ((jwin + wn * WNS + ni * 16 + lc) != ig);
        rp = fmaxf(rp, posok ? v : -3e38f);
        rn = fminf(rn, same ? 3e38f : v);
        if (!STRAD) {                              // j-mining: sq_i - 2dot per column
          float v2 = fmaf(-2.f, a, si);
          jp[ni] = fmaxf(jp[ni], same ? v2 : -3e38f);
          jn[ni] = fminf(jn[ni], same ? 3e38f : v2);
        }
      }
      rpos[mi * 4 + r] = rp; rneg[mi * 4 + r] = rn;
    }
  }
}

// ---------------- epilogue part B: shuffle-reduce + LDS writes (the latency blanket) -----
template<bool STRAD, int NI, int WNS>
__device__ __forceinline__ void epi_store(
    float (&rpos)[16], float (&rneg)[16], float (&jp)[8], float (&jn)[8],
    int wm, int wn, int quad, int lc,
    unsigned (*ibuf)[128][2], unsigned (*jbuf)[256][2]) {
  #pragma unroll
  for (int m = 1; m <= 8; m <<= 1)
    #pragma unroll
    for (int x = 0; x < 16; x++) {
      rpos[x] = fmaxf(rpos[x], __shfl_xor(rpos[x], m));
      rneg[x] = fminf(rneg[x], __shfl_xor(rneg[x], m));
    }
  if (lc == 0) {
    #pragma unroll
    for (int mi = 0; mi < 4; mi++)
      #pragma unroll
      for (int r = 0; r < 4; r++) {
        int row = wm * 64 + mi * 16 + quad * 4 + r;
        ibuf[wn][row][0] = enc(rpos[mi * 4 + r]);
        ibuf[wn][row][1] = enc(rneg[mi * 4 + r]);
      }
  }
  if (!STRAD) {
    #pragma unroll
    for (int m = 16; m <= 32; m <<= 1)
      #pragma unroll
      for (int x = 0; x < NI; x++) {
        jp[x] = fmaxf(jp[x], __shfl_xor(jp[x], m));
        jn[x] = fminf(jn[x], __shfl_xor(jn[x], m));
      }
    if (quad == 0) {
      #pragma unroll
      for (int ni = 0; ni < NI; ni++) {
        int col = wn * WNS + ni * 16 + lc;
        jbuf[wm][col][0] = enc(jp[ni]);
        jbuf[wm][col][1] = enc(jn[ni]);
      }
    }
  }
}

// ---------------- main: R3 loop + next-tile step-0 prefetch AFTER acc dies ---------------
// R10 post-mortem: prefetch-before-epilogue kept acc (128 regs) live across the
// issue -> scratch spill (WRITE 6->21MB), +15us. Fix: order is
//   gemm -> epi_acc (acc dies; sched_barrier(0) pins it) -> tshare+barrier
//   -> prefetch issue (live set ~80 regs) -> epi_store (shuffle blanket)
//   -> barrier (drains vmcnt AFTER ~500cyc of blanket) -> stores.
// Hazards: last ds_reads precede epi_acc which precedes the barrier -> Asm/Bsm
// overwrite safe; epi_store writes ibuf/jbuf (separate buffers, no clash with
// in-flight staging); stores read ibuf after barrier; next ibuf writes are 15+
// barriers away. Quarters on the proven BK=64 path.
__global__ __launch_bounds__(256, 2) void triplet_mfma(
    const unsigned short* __restrict__ Xb, const float* __restrict__ sq,
    const int* __restrict__ labels, unsigned* __restrict__ ctrl,
    unsigned* __restrict__ pos_i, unsigned* __restrict__ neg_i,
    unsigned* __restrict__ pos_j, unsigned* __restrict__ neg_j) {
  __shared__ __align__(16) unsigned short Asm[128 * 64];  // 16 KB
  __shared__ __align__(16) unsigned short Bsm[256 * 64];  // 32 KB
  __shared__ unsigned ibuf[2][128][2];                    // 2 KB (separate: part B
  __shared__ unsigned jbuf[2][256][2];                    // 4 KB  runs during staging)
  __shared__ int tshare;

  int tid = threadIdx.x;
  int wave = tid >> 6, lane = tid & 63;
  int wm = wave >> 1, wn = wave & 1;
  int quad = lane >> 4, lc = lane & 15;
  int rc = lane >> 3;
  int gcol = ((lane & 7) ^ rc) * 8;          // XOR swizzle (verified: 0 conflicts)

  if (tid == 0) tshare = (int)atomicAdd(&ctrl[3], 1u);
  __syncthreads();
  int t = tshare;
  if (t >= NTILE) return;

  int It, Js, q; bool strad;
  decode_tile(t, It, Js, q, strad);
  int i0 = It * 128;
  int jw = Js * 256 + (q >= 0 ? q * 64 : 0);
  if (q >= 0) stage_slab<2>(Xb, i0, jw, 0, Asm, Bsm, wave, rc, gcol);
  else        stage_slab<8>(Xb, i0, jw, 0, Asm, Bsm, wave, rc, gcol);

  for (;;) {
    f32x4 acc[4][8];
    #pragma unroll
    for (int mi = 0; mi < 4; mi++)
      #pragma unroll
      for (int ni = 0; ni < 8; ni++)
        acc[mi][ni] = (f32x4){0.f, 0.f, 0.f, 0.f};

    if (q >= 0) gemm_pf<2>(Xb, i0, jw, Asm, Bsm, wave, wm, wn, quad, lc, rc, gcol, acc);
    else        gemm_pf<8>(Xb, i0, jw, Asm, Bsm, wave, wm, wn, quad, lc, rc, gcol, acc);

    // part A: consume acc (register-only). sched_barrier pins it BEFORE the
    // prefetch so the compiler cannot sink it and re-inflate acc's live range.
    float rpos[16], rneg[16], jp[8], jn[8];
    if (q >= 0)
      epi_acc<false, 2, 32>(acc, sq, labels, i0, jw, wm, wn, quad, lc, rpos, rneg, jp, jn);
    else if (strad)
      epi_acc<true, 8, 128>(acc, sq, labels, i0, jw, wm, wn, quad, lc, rpos, rneg, jp, jn);
    else
      epi_acc<false, 8, 128>(acc, sq, labels, i0, jw, wm, wn, quad, lc, rpos, rneg, jp, jn);
    __builtin_amdgcn_sched_barrier(0);

    // fetch next tile; barrier publishes tshare AND orders the K-loop's last
    // ds_reads before the prefetch's Asm/Bsm writes
    if (tid == 0) tshare = (int)atomicAdd(&ctrl[3], 1u);
    __syncthreads();
    int tn = tshare;
    int nIt = 0, nJs = 0, nq = -1; bool nstrad = false; int ni0 = 0, njw = 0;
    if (tn < NTILE) {
      decode_tile(tn, nIt, nJs, nq, nstrad);
      ni0 = nIt * 128;
      njw = nJs * 256 + (nq >= 0 ? nq * 64 : 0);
      if (nq >= 0) stage_slab<2>(Xb, ni0, njw, 0, Asm, Bsm, wave, rc, gcol);
      else         stage_slab<8>(Xb, ni0, njw, 0, Asm, Bsm, wave, rc, gcol);
    }

    // part B: shuffle-reduce + ibuf/jbuf writes — hides the prefetch latency
    if (q >= 0)
      epi_store<false, 2, 32>(rpos, rneg, jp, jn, wm, wn, quad, lc, ibuf, jbuf);
    else if (strad)
      epi_store<true, 8, 128>(rpos, rneg, jp, jn, wm, wn, quad, lc, ibuf, jbuf);
    else
      epi_store<false, 8, 128>(rpos, rneg, jp, jn, wm, wn, quad, lc, ibuf, jbuf);
    __syncthreads();

    // in-block combine + stores to slots (tile t)
    if (q >= 0) {
      // quarter: 4 siblings share i-rows of slot (Js, i0..) -> atomic merge
      if (tid < 128) {
        unsigned p = max(ibuf[0][tid][0], ibuf[1][tid][0]);
        unsigned n = min(ibuf[0][tid][1], ibuf[1][tid][1]);
        atomicMax(&pos_i[(size_t)Js * BATCH + i0 + tid], p);
        atomicMin(&neg_i[(size_t)Js * BATCH + i0 + tid], n);
      }
      if (tid < 64) {   // j-cols disjoint across siblings -> plain stores
        unsigned p = max(jbuf[0][tid][0], jbuf[1][tid][0]);
        unsigned n = min(jbuf[0][tid][1], jbuf[1][tid][1]);
        pos_j[(size_t)It * BATCH + jw + tid] = p;
        neg_j[(size_t)It * BATCH + jw + tid] = n;
      }
    } else {
      if (tid < 128) {
        unsigned p = max(ibuf[0][tid][0], ibuf[1][tid][0]);
        unsigned n = min(ibuf[0][tid][1], ibuf[1][tid][1]);
        pos_i[(size_t)Js * BATCH + i0 + tid] = p;
        neg_i[(size_t)Js * BATCH + i0 + tid] = n;
      }
      if (!strad) {
        unsigned p = max(jbuf[0][tid][0], jbuf[1][tid][0]);
        unsigned n = min(jbuf[0][tid][1], jbuf[1][tid][1]);
        pos_j[(size_t)It * BATCH + jw + tid] = p;
        neg_j[(size_t)It * BATCH + jw + tid] = n;
      }
    }
    // no trailing sync: ibuf/jbuf next written only after t+1's K-loop barriers

    if (tn >= NTILE) break;
    t = tn; It = nIt; Js = nJs; q = nq; strad = nstrad; i0 = ni0; jw = njw;
  }
}

// ---------------- final v2: 128 blocks x 64 rows, 4-wave slot split ----------------
__global__ __launch_bounds__(256) void final_kernel(
    const unsigned* __restrict__ pos_i, const unsigned* __restrict__ neg_i,
    const unsigned* __restrict__ pos_j, const unsigned* __restrict__ neg_j,
    const float* __restrict__ sq, unsigned* __restrict__ ctrl,
    float* __restrict__ out) {
  __shared__ unsigned fbuf[4][64][2];
  int wave = threadIdx.x >> 6, lane = threadIdx.x & 63;
  int r = blockIdx.x * 64 + lane;           // rows coalesced across lanes
  unsigned pe = 0u, ne = 0xFFFFFFFFu;       // sentinels lose every comparison
  #pragma unroll
  for (int k = 0; k < 24; k++) {
    int s = wave * 24 + k;                  // slot id: [0,32)=i-slots, [32,96)=j-slots
    const unsigned* ps = (s < 32) ? pos_i + (size_t)s * BATCH
                                  : pos_j + (size_t)(s - 32) * BATCH;
    const unsigned* ns = (s < 32) ? neg_i + (size_t)s * BATCH
                                  : neg_j + (size_t)(s - 32) * BATCH;
    pe = max(pe, ps[r]);
    ne = min(ne, ns[r]);
  }
  fbuf[wave][lane][0] = pe;
  fbuf[wave][lane][1] = ne;
  __syncthreads();
  if (wave == 0) {
    pe = max(max(fbuf[0][lane][0], fbuf[1][lane][0]),
             max(fbuf[2][lane][0], fbuf[3][lane][0]));
    ne = min(min(fbuf[0][lane][1], fbuf[1][lane][1]),
             min(fbuf[2][lane][1], fbuf[3][lane][1]));
    float p = dec(pe), n = dec(ne);
    float term = 0.f, cnt = 0.f;
    if (p > -1e37f && n < 1e37f) {          // sentinel decodes fail => invalid row
      float si = sq[r];
      float dp = sqrtf(fmaxf(si + p, 0.f) + 1e-16f);
      float dn = sqrtf(fmaxf(si + n, 0.f) + 1e-16f);
      term = fmaxf(dp - dn + 0.3f, 0.f);
      cnt = 1.f;
    }
    #pragma unroll
    for (int off = 32; off > 0; off >>= 1) {
      term += __shfl_down(term, off);
      cnt  += __shfl_down(cnt, off);
    }
    if (lane == 0) {
      atomicAdd((float*)&ctrl[0], term);
      atomicAdd((float*)&ctrl[1], cnt);
      __threadfence();
      unsigned t = atomicAdd(&ctrl[2], 1u);
      if (t == NFIN - 1) {
        float S = atomicAdd((float*)&ctrl[0], 0.f);
        float C = atomicAdd((float*)&ctrl[1], 0.f);
        out[0] = S / fmaxf(C, 1.f);
      }
    }
  }
}

extern "C" void kernel_launch(void* const* d_in, const int* in_sizes, int n_in,
                              void* d_out, int out_size, void* d_ws, size_t ws_size,
                              hipStream_t stream) {
  const float* X      = (const float*)d_in[0];
  const int*   labels = (const int*)d_in[1];
  float* out = (float*)d_out;
  char* ws = (char*)d_ws;

  const size_t SLOT = (size_t)BATCH * 4;                 // 32 KB per slot
  unsigned short* Xb = (unsigned short*)ws;              // 8 MB
  float* sq      = (float*)(ws + (8u << 20));            // 32 KB
  unsigned* ctrl = (unsigned*)(ws + (8u << 20) + (32u << 10)); // sums|ticket|queue
  char*  posb = ws + (8u << 20) + (64u << 10);           // 96 slots = 3 MB
  char*  negb = posb + 96 * SLOT;                        // 96 slots = 3 MB
  unsigned* pos_i = (unsigned*)posb;                     // 32 slots keyed Js
  unsigned* pos_j = (unsigned*)(posb + 32 * SLOT);       // 64 slots keyed It
  unsigned* neg_i = (unsigned*)negb;
  unsigned* neg_j = (unsigned*)(negb + 32 * SLOT);

  prep_kernel<<<BATCH / 4, 256, 0, stream>>>(X, Xb, sq, ctrl,
                                             (uint4*)posb, (uint4*)negb);
  triplet_mfma<<<512, 256, 0, stream>>>(Xb, sq, labels, ctrl,
                                        pos_i, neg_i, pos_j, neg_j);
  final_kernel<<<NFIN, 256, 0, stream>>>(pos_i, neg_i, pos_j, neg_j, sq, ctrl, out);
}

// Round 12
// 132.500 us; speedup vs baseline: 1.1287x; 1.1287x over previous
//
#include <hip/hip_runtime.h>

#define BATCH 8192
#define DIM   512
// 64 straddle + 960 full above-diag + 128 quarter tiles (last 32 parents split 4-way in j)
#define NTILE 1152
#define NFIN  128          // final-kernel blocks

typedef __attribute__((ext_vector_type(4))) float  f32x4;
typedef __attribute__((ext_vector_type(8))) __bf16 bf16x8;

__device__ __forceinline__ unsigned short f2bf(float x) {
  unsigned u = __float_as_uint(x);
  u = (u + 0x7FFFu + ((u >> 16) & 1u)) >> 16;   // RNE
  return (unsigned short)u;
}

__device__ __forceinline__ void load_lds16(const void* g, void* l) {
  __builtin_amdgcn_global_load_lds(
      (__attribute__((address_space(1))) void*)(g),
      (__attribute__((address_space(3))) void*)(l), 16, 0, 0);
}

// monotone float <-> uint encoding (order-preserving); sentinels 0x00000000 / 0xFFFFFFFF
__device__ __forceinline__ unsigned enc(float f) {
  unsigned u = __float_as_uint(f);
  return u ^ (unsigned)(((int)u >> 31) | 0x80000000);
}
__device__ __forceinline__ float dec(unsigned k) {
  unsigned u = (k & 0x80000000u) ? (k ^ 0x80000000u) : ~k;
  return __uint_as_float(u);
}

// ---------------- prep: fp32->bf16, row norms, sentinel seeding, ctrl zeroing --------------
__global__ __launch_bounds__(256) void prep_kernel(
    const float* __restrict__ X, unsigned short* __restrict__ Xb,
    float* __restrict__ sq, unsigned* __restrict__ ctrl,
    uint4* __restrict__ pos4, uint4* __restrict__ neg4) {
  int gid = blockIdx.x * 256 + threadIdx.x;
  if (gid == 0) {
    ((float*)ctrl)[0] = 0.f;                   // sum of terms
    ((float*)ctrl)[1] = 0.f;                   // count
    ctrl[2] = 0u;                              // finish ticket
    ctrl[3] = 0u;                              // tile queue head
  }
  if (gid < 196608) {                          // 96 slots * 8192 * 4B / 16B
    pos4[gid] = (uint4){0u, 0u, 0u, 0u};       // enc-min sentinel (loses every max)
    neg4[gid] = (uint4){~0u, ~0u, ~0u, ~0u};   // enc-max sentinel (loses every min)
  }
  int wave = threadIdx.x >> 6, lane = threadIdx.x & 63;
  int row = blockIdx.x * 4 + wave;             // 2048 blocks * 4 waves = 8192 rows
  const float4* xr = (const float4*)(X + (size_t)row * DIM);
  float4 a = xr[lane * 2];
  float4 b = xr[lane * 2 + 1];
  float s = a.x*a.x + a.y*a.y + a.z*a.z + a.w*a.w
          + b.x*b.x + b.y*b.y + b.z*b.z + b.w*b.w;
  uint4 p;
  p.x = (unsigned)f2bf(a.x) | ((unsigned)f2bf(a.y) << 16);
  p.y = (unsigned)f2bf(a.z) | ((unsigned)f2bf(a.w) << 16);
  p.z = (unsigned)f2bf(b.x) | ((unsigned)f2bf(b.y) << 16);
  p.w = (unsigned)f2bf(b.z) | ((unsigned)f2bf(b.w) << 16);
  ((uint4*)(Xb + (size_t)row * DIM))[lane] = p;
  #pragma unroll
  for (int off = 32; off > 0; off >>= 1) s += __shfl_down(s, off);
  if (lane == 0) sq[row] = s;
}

// ---------------- K-loop for one 128 x (NI*32) tile (R3-verbatim + T5 setprio) ----
// NI=8,WNS=128: full 128x256 tile.  NI=2,WNS=32: 128x64 quarter.
// T5 regime check: 2 INDEPENDENT queue-driven blocks/CU at desynced phases (the
// m191-attn regime, not m190's lockstep null) — setprio biases the CU scheduler
// toward the MFMA-entering wave while the other block issues staging loads.
template<int NI>
__device__ __forceinline__ void gemm_tile(
    const unsigned short* __restrict__ Xb, int i0, int jw,
    unsigned short* Asm, unsigned short* Bsm,
    int wave, int wm, int wn, int quad, int lc, int rc, int gcol,
    f32x4 (&acc)[4][8]) {
  for (int k0 = 0; k0 < DIM; k0 += 64) {
    #pragma unroll
    for (int tt = 0; tt < 4; tt++) {
      int c = wave * 4 + tt;
      int row = c * 8 + rc;
      load_lds16(Xb + (size_t)(i0 + row) * DIM + k0 + gcol, &Asm[c * 512]);
    }
    #pragma unroll
    for (int tt = 0; tt < NI; tt++) {          // NI loads/thread covers NI*32 B-rows
      int c = wave * NI + tt;
      int row = c * 8 + rc;
      load_lds16(Xb + (size_t)(jw + row) * DIM + k0 + gcol, &Bsm[c * 512]);
    }
    __syncthreads();
    #pragma unroll
    for (int kk = 0; kk < 64; kk += 32) {
      int kc = kk >> 3;
      int asel = ((kc + quad) ^ (lc & 7)) * 8;
      bf16x8 af[4], bfr[NI];
      #pragma unroll
      for (int mi = 0; mi < 4; mi++)
        af[mi] = *(const bf16x8*)&Asm[(wm * 64 + mi * 16 + lc) * 64 + asel];
      #pragma unroll
      for (int ni = 0; ni < NI; ni++)
        bfr[ni] = *(const bf16x8*)&Bsm[(wn * (NI * 16) + ni * 16 + lc) * 64 + asel];
      __builtin_amdgcn_s_setprio(1);           // T5: favor MFMA over other block's VMEM
      #pragma unroll
      for (int mi = 0; mi < 4; mi++)
        #pragma unroll
        for (int ni = 0; ni < NI; ni++)
          acc[mi][ni] = __builtin_amdgcn_mfma_f32_16x16x32_bf16(
              af[mi], bfr[ni], acc[mi][ni], 0, 0, 0);
      __builtin_amdgcn_s_setprio(0);
    }
    __syncthreads();
  }
}

// Epilogue: i-mining always; j-mining (transposed) unless STRAD (diag straddle).
template<bool STRAD, int NI, int WNS>
__device__ __forceinline__ void epilogue(
    const f32x4 (&acc)[4][8], const float* __restrict__ sq,
    const int* __restrict__ labels,
    int i0, int jwin, int wm, int wn, int quad, int lc,
    unsigned (*ibuf)[128][2], unsigned (*jbuf)[256][2]) {
  float sqj_r[NI]; int labj_r[NI];
  #pragma unroll
  for (int ni = 0; ni < NI; ni++) {
    int j = jwin + wn * WNS + ni * 16 + lc;
    sqj_r[ni] = sq[j]; labj_r[ni] = labels[j];
  }
  float rpos[16], rneg[16];
  float jp[NI], jn[NI];
  #pragma unroll
  for (int x = 0; x < NI; x++) { jp[x] = -3e38f; jn[x] = 3e38f; }
  #pragma unroll
  for (int mi = 0; mi < 4; mi++) {
    #pragma unroll
    for (int r = 0; r < 4; r++) {
      int ig = i0 + wm * 64 + mi * 16 + quad * 4 + r;
      int li = labels[ig];
      float si = sq[ig];
      float rp = -3e38f, rn = 3e38f;
      #pragma unroll
      for (int ni = 0; ni < NI; ni++) {
        float a = acc[mi][ni][r];
        float v = fmaf(-2.f, a, sqj_r[ni]);        // sq_j - 2dot (sq_i added at end)
        bool same = (li == labj_r[ni]);
        bool posok = same;
        if (STRAD) posok = same && ((jwin + wn * WNS + ni * 16 + lc) != ig);
        rp = fmaxf(rp, posok ? v : -3e38f);
        rn = fminf(rn, same ? 3e38f : v);
        if (!STRAD) {                              // j-mining: sq_i - 2dot per column
          float v2 = fmaf(-2.f, a, si);
          jp[ni] = fmaxf(jp[ni], same ? v2 : -3e38f);
          jn[ni] = fminf(jn[ni], same ? 3e38f : v2);
        }
      }
      rpos[mi * 4 + r] = rp; rneg[mi * 4 + r] = rn;
    }
  }
  #pragma unroll
  for (int m = 1; m <= 8; m <<= 1)
    #pragma unroll
    for (int x = 0; x < 16; x++) {
      rpos[x] = fmaxf(rpos[x], __shfl_xor(rpos[x], m));
      rneg[x] = fminf(rneg[x], __shfl_xor(rneg[x], m));
    }
  if (lc == 0) {
    #pragma unroll
    for (int mi = 0; mi < 4; mi++)
      #pragma unroll
      for (int r = 0; r < 4; r++) {
        int row = wm * 64 + mi * 16 + quad * 4 + r;
        ibuf[wn][row][0] = enc(rpos[mi * 4 + r]);
        ibuf[wn][row][1] = enc(rneg[mi * 4 + r]);
      }
  }
  if (!STRAD) {
    #pragma unroll
    for (int m = 16; m <= 32; m <<= 1)
      #pragma unroll
      for (int x = 0; x < NI; x++) {
        jp[x] = fmaxf(jp[x], __shfl_xor(jp[x], m));
        jn[x] = fminf(jn[x], __shfl_xor(jn[x], m));
      }
    if (quad == 0) {
      #pragma unroll
      for (int ni = 0; ni < NI; ni++) {
        int col = wn * WNS + ni * 16 + lc;
        jbuf[wm][col][0] = enc(jp[ni]);
        jbuf[wm][col][1] = enc(jn[ni]);
      }
    }
  }
}

// ---------------- main: R9 champion structure + T5 setprio -------------------------------
// R10/R11 post-mortem: prefetch-under-epilogue spills regardless of placement
// (acc 128 regs or the reduce state push peak pressure over the 2-block budget;
// WRITE 21/33MB). R4/R5: hand pipelines lose to the compiler schedule. The
// 128x256/2-block structure's K-loop is at its source-level floor — this round
// isolates the one untried catalog lever (T5) on the proven R9 base.
__global__ __launch_bounds__(256, 2) void triplet_mfma(
    const unsigned short* __restrict__ Xb, const float* __restrict__ sq,
    const int* __restrict__ labels, unsigned* __restrict__ ctrl,
    unsigned* __restrict__ pos_i, unsigned* __restrict__ neg_i,
    unsigned* __restrict__ pos_j, unsigned* __restrict__ neg_j) {
  __shared__ __align__(16) unsigned short Asm[128 * 64];  // 16 KB
  __shared__ __align__(16) unsigned short Bsm[256 * 64];  // 32 KB
  __shared__ int tshare;

  // overlay: ibuf at Asm[0..1023] (2KB), jbuf at Asm[1024..3071] (4KB)
  unsigned (*ibuf)[128][2] = reinterpret_cast<unsigned (*)[128][2]>(&Asm[0]);
  unsigned (*jbuf)[256][2] = reinterpret_cast<unsigned (*)[256][2]>(&Asm[1024]);

  int tid = threadIdx.x;
  int wave = tid >> 6, lane = tid & 63;
  int wm = wave >> 1, wn = wave & 1;
  int quad = lane >> 4, lc = lane & 15;
  int rc = lane >> 3;
  int gcol = ((lane & 7) ^ rc) * 8;          // XOR swizzle (verified: 0 conflicts)

  for (;;) {
    if (tid == 0) tshare = (int)atomicAdd(&ctrl[3], 1u);
    __syncthreads();
    int t = tshare;
    if (t >= NTILE) break;

    int It = 0, Js = 0, q = -1; bool strad = false;
    if (t < 64) { It = t; Js = t >> 1; strad = true; }
    else {
      int u;
      if (t < 1024) u = t - 64;                       // full above-diag: u in [0,960)
      else { q = (t - 1024) & 3; u = 960 + ((t - 1024) >> 2); }  // quarters: u in [960,992)
      for (int s = 0; s < 64; s++) {
        int c = 31 - (s >> 1);
        if (u < c) { It = s; Js = (s >> 1) + 1 + u; break; }
        u -= c;
      }
    }
    int i0 = It * 128;
    int jw = Js * 256 + (q >= 0 ? q * 64 : 0);

    f32x4 acc[4][8];
    #pragma unroll
    for (int mi = 0; mi < 4; mi++)
      #pragma unroll
      for (int ni = 0; ni < 8; ni++)
        acc[mi][ni] = (f32x4){0.f, 0.f, 0.f, 0.f};

    if (q >= 0) {
      gemm_tile<2>(Xb, i0, jw, Asm, Bsm, wave, wm, wn, quad, lc, rc, gcol, acc);
      epilogue<false, 2, 32>(acc, sq, labels, i0, jw, wm, wn, quad, lc, ibuf, jbuf);
    } else {
      gemm_tile<8>(Xb, i0, jw, Asm, Bsm, wave, wm, wn, quad, lc, rc, gcol, acc);
      if (strad)
        epilogue<true, 8, 128>(acc, sq, labels, i0, jw, wm, wn, quad, lc, ibuf, jbuf);
      else
        epilogue<false, 8, 128>(acc, sq, labels, i0, jw, wm, wn, quad, lc, ibuf, jbuf);
    }
    __syncthreads();

    // in-block combine + stores to slots
    if (q >= 0) {
      // quarter: 4 siblings share i-rows of slot (Js, i0..) -> atomic merge
      if (tid < 128) {
        unsigned p = max(ibuf[0][tid][0], ibuf[1][tid][0]);
        unsigned n = min(ibuf[0][tid][1], ibuf[1][tid][1]);
        atomicMax(&pos_i[(size_t)Js * BATCH + i0 + tid], p);
        atomicMin(&neg_i[(size_t)Js * BATCH + i0 + tid], n);
      }
      if (tid < 64) {   // j-cols disjoint across siblings -> plain stores
        unsigned p = max(jbuf[0][tid][0], jbuf[1][tid][0]);
        unsigned n = min(jbuf[0][tid][1], jbuf[1][tid][1]);
        pos_j[(size_t)It * BATCH + jw + tid] = p;
        neg_j[(size_t)It * BATCH + jw + tid] = n;
      }
    } else {
      if (tid < 128) {
        unsigned p = max(ibuf[0][tid][0], ibuf[1][tid][0]);
        unsigned n = min(ibuf[0][tid][1], ibuf[1][tid][1]);
        pos_i[(size_t)Js * BATCH + i0 + tid] = p;
        neg_i[(size_t)Js * BATCH + i0 + tid] = n;
      }
      if (!strad) {
        unsigned p = max(jbuf[0][tid][0], jbuf[1][tid][0]);
        unsigned n = min(jbuf[0][tid][1], jbuf[1][tid][1]);
        pos_j[(size_t)It * BATCH + jw + tid] = p;
        neg_j[(size_t)It * BATCH + jw + tid] = n;
      }
    }
    __syncthreads();   // protect overlay reads from next tile's staging writes
  }
}

// ---------------- final v2: 128 blocks x 64 rows, 4-wave slot split ----------------
__global__ __launch_bounds__(256) void final_kernel(
    const unsigned* __restrict__ pos_i, const unsigned* __restrict__ neg_i,
    const unsigned* __restrict__ pos_j, const unsigned* __restrict__ neg_j,
    const float* __restrict__ sq, unsigned* __restrict__ ctrl,
    float* __restrict__ out) {
  __shared__ unsigned fbuf[4][64][2];
  int wave = threadIdx.x >> 6, lane = threadIdx.x & 63;
  int r = blockIdx.x * 64 + lane;           // rows coalesced across lanes
  unsigned pe = 0u, ne = 0xFFFFFFFFu;       // sentinels lose every comparison
  #pragma unroll
  for (int k = 0; k < 24; k++) {
    int s = wave * 24 + k;                  // slot id: [0,32)=i-slots, [32,96)=j-slots
    const unsigned* ps = (s < 32) ? pos_i + (size_t)s * BATCH
                                  : pos_j + (size_t)(s - 32) * BATCH;
    const unsigned* ns = (s < 32) ? neg_i + (size_t)s * BATCH
                                  : neg_j + (size_t)(s - 32) * BATCH;
    pe = max(pe, ps[r]);
    ne = min(ne, ns[r]);
  }
  fbuf[wave][lane][0] = pe;
  fbuf[wave][lane][1] = ne;
  __syncthreads();
  if (wave == 0) {
    pe = max(max(fbuf[0][lane][0], fbuf[1][lane][0]),
             max(fbuf[2][lane][0], fbuf[3][lane][0]));
    ne = min(min(fbuf[0][lane][1], fbuf[1][lane][1]),
             min(fbuf[2][lane][1], fbuf[3][lane][1]));
    float p = dec(pe), n = dec(ne);
    float term = 0.f, cnt = 0.f;
    if (p > -1e37f && n < 1e37f) {          // sentinel decodes fail => invalid row
      float si = sq[r];
      float dp = sqrtf(fmaxf(si + p, 0.f) + 1e-16f);
      float dn = sqrtf(fmaxf(si + n, 0.f) + 1e-16f);
      term = fmaxf(dp - dn + 0.3f, 0.f);
      cnt = 1.f;
    }
    #pragma unroll
    for (int off = 32; off > 0; off >>= 1) {
      term += __shfl_down(term, off);
      cnt  += __shfl_down(cnt, off);
    }
    if (lane == 0) {
      atomicAdd((float*)&ctrl[0], term);
      atomicAdd((float*)&ctrl[1], cnt);
      __threadfence();
      unsigned t = atomicAdd(&ctrl[2], 1u);
      if (t == NFIN - 1) {
        float S = atomicAdd((float*)&ctrl[0], 0.f);
        float C = atomicAdd((float*)&ctrl[1], 0.f);
        out[0] = S / fmaxf(C, 1.f);
      }
    }
  }
}

extern "C" void kernel_launch(void* const* d_in, const int* in_sizes, int n_in,
                              void* d_out, int out_size, void* d_ws, size_t ws_size,
                              hipStream_t stream) {
  const float* X      = (const float*)d_in[0];
  const int*   labels = (const int*)d_in[1];
  float* out = (float*)d_out;
  char* ws = (char*)d_ws;

  const size_t SLOT = (size_t)BATCH * 4;                 // 32 KB per slot
  unsigned short* Xb = (unsigned short*)ws;              // 8 MB
  float* sq      = (float*)(ws + (8u << 20));            // 32 KB
  unsigned* ctrl = (unsigned*)(ws + (8u << 20) + (32u << 10)); // sums|ticket|queue
  char*  posb = ws + (8u << 20) + (64u << 10);           // 96 slots = 3 MB
  char*  negb = posb + 96 * SLOT;                        // 96 slots = 3 MB
  unsigned* pos_i = (unsigned*)posb;                     // 32 slots keyed Js
  unsigned* pos_j = (unsigned*)(posb + 32 * SLOT);       // 64 slots keyed It
  unsigned* neg_i = (unsigned*)negb;
  unsigned* neg_j = (unsigned*)(negb + 32 * SLOT);

  prep_kernel<<<BATCH / 4, 256, 0, stream>>>(X, Xb, sq, ctrl,
                                             (uint4*)posb, (uint4*)negb);
  triplet_mfma<<<512, 256, 0, stream>>>(Xb, sq, labels, ctrl,
                                        pos_i, neg_i, pos_j, neg_j);
  final_kernel<<<NFIN, 256, 0, stream>>>(pos_i, neg_i, pos_j, neg_j, sq, ctrl, out);
}